// Round 17
// baseline (482.672 us; speedup 1.0000x reference)
//
#include <hip/hip_runtime.h>
#include <hip/hip_fp16.h>

// ---- problem constants ----
#define NROWS   32768
#define MT      64          // rows per block
#define NTH     512         // threads per block (8 waves; wave owns 64 cols, 2 passes of 32)
#define OS      148         // LDS out-params stride in float (138 + pad; 16B-aligned rows)
#define BND     3.0f

typedef _Float16 half_t;
typedef __attribute__((ext_vector_type(8))) _Float16 f16x8;
typedef __attribute__((ext_vector_type(4))) _Float16 f16x4;
typedef __attribute__((ext_vector_type(4))) float    f32x4;

// R17: R16 + fused {spline + permute-scatter + logdet-atomic} phase:
//  - spline thread (m,j) scatters its result to k_out = iperm[l][6+j] of
//    xbuf[cur^1] (and inpb if k_out<6); also copies the j-th x1-dest col
//    (exactly 6 cols k have perm[k]<6 -> 1:1 with 6 spline threads/row).
//  - logdet accumulated with LDS atomicAdd(&ldtot[m], lad); ldpart deleted.
//  - iperm / x1-dest tables precomputed in prologue from global perms.
//  Net: 6 -> 5 __syncthreads()/layer, one LDS pass deleted.
// Carried: prologue-built inpb + ping-pong xbuf (R16), __logf spline (R5),
// W-ring depth 8 (R6), allocator law (R7-R12), 468-bug ban on 2-blk/CU
// restructures (R2-R4), 32x32 MFMA dead end (R14).

__global__ void pack_frag(const float* __restrict__ src, half_t* __restrict__ dst,
                          int K, int Nn, int NT, int KS) {
  int l = blockIdx.z;
  int frag = blockIdx.x * 4 + (threadIdx.x >> 6);
  int lane = threadIdx.x & 63;
  int NF = NT * KS;
  if (frag >= NF) return;
  int nt = frag / KS, ks = frag - nt * KS;
  int n = nt * 16 + (lane & 15);
  int kb = ks * 32 + (lane >> 4) * 8;
  f16x8 v;
#pragma unroll
  for (int e = 0; e < 8; e++) {
    int k = kb + e;
    v[e] = (k < K && n < Nn) ? (half_t)src[((size_t)l * K + k) * Nn + n] : (half_t)0.f;
  }
  *(f16x8*)(dst + ((size_t)l * NF + frag) * 512 + lane * 8) = v;
}

__device__ __forceinline__ float elu_f(float v) {
  return v > 0.f ? v : (__expf(v) - 1.f);
}

// GEMM: [64 x K] (LDS fp16, fragment-ordered, KSA ksteps) @ [K x 512] (global)
// -> elu(. + bias) -> dst LDS fp16 (fragment-ordered, 16 ksteps).
// Wave w covers cols [w*64, w*64+64) in TWO 32-col passes;
// pass 0's k-loop tail prefills pass 1's rings (all 8 lead steps).
// TRANSPOSED MFMA: mfma(W,A,acc) -> lane holds 4 consecutive n at row m.
__device__ __forceinline__ void gemm_elu(
    const half_t* A, int KSA, int ksteps,
    const half_t* __restrict__ Wf, int KSW,
    const float* __restrict__ bias,
    half_t* dst,
    int w, int lane, int lm, int lk) {
  f16x8 a[2][4], b[8][2];
#pragma unroll
  for (int half = 0; half < 2; half++) {
    const int ntb = w * 4 + half * 2;
    f32x4 acc[4][2];
#pragma unroll
    for (int i = 0; i < 4; i++)
#pragma unroll
      for (int j = 0; j < 2; j++) acc[i][j] = (f32x4){0.f, 0.f, 0.f, 0.f};

    const bool prefilled = (ksteps == 16) && (half == 1);
    if (!prefilled) {
#pragma unroll
      for (int s = 0; s < 8; s++)
        if (s < ksteps) {
#pragma unroll
          for (int nt = 0; nt < 2; nt++)
            b[s][nt] = *(const f16x8*)(Wf + ((size_t)((ntb + nt) * KSW + s)) * 512 + lane * 8);
        }
#pragma unroll
      for (int s = 0; s < 2; s++)
        if (s < ksteps) {
#pragma unroll
          for (int mf = 0; mf < 4; mf++)
            a[s][mf] = *(const f16x8*)(A + ((size_t)(mf * KSA + s)) * 512 + lane * 8);
        }
    }
#pragma unroll
    for (int ks = 0; ks < ksteps; ks++) {
      const int sl = ks & 7, asx = ks & 1;
#pragma unroll
      for (int nt = 0; nt < 2; nt++)
#pragma unroll
        for (int mf = 0; mf < 4; mf++)
          acc[mf][nt] = __builtin_amdgcn_mfma_f32_16x16x32_f16(b[sl][nt], a[asx][mf], acc[mf][nt], 0, 0, 0);
      // B refill: own steps (depth 8), then (pass 0 only) pass-1 steps 0..7
      if (ks + 8 < ksteps) {
#pragma unroll
        for (int nt = 0; nt < 2; nt++)
          b[sl][nt] = *(const f16x8*)(Wf + ((size_t)((ntb + nt) * KSW + ks + 8)) * 512 + lane * 8);
      } else if (ksteps == 16 && half == 0) {
#pragma unroll
        for (int nt = 0; nt < 2; nt++)
          b[sl][nt] = *(const f16x8*)(Wf + ((size_t)((ntb + 2 + nt) * KSW + (ks - 8))) * 512 + lane * 8);
      }
      // A refill: own chunks, then (pass 0 only) chunks 0..1 for pass 1
      if (ks + 2 < ksteps) {
#pragma unroll
        for (int mf = 0; mf < 4; mf++)
          a[asx][mf] = *(const f16x8*)(A + ((size_t)(mf * KSA + ks + 2)) * 512 + lane * 8);
      } else if (ksteps == 16 && half == 0) {
#pragma unroll
        for (int mf = 0; mf < 4; mf++)
          a[asx][mf] = *(const f16x8*)(A + ((size_t)(mf * KSA + (ks - 14))) * 512 + lane * 8);
      }
    }
    // epilogue -> dst in A-fragment order: element (m = mf*16+lm, k = n0+r)
    // frag = mf*16 + (w*2+half); lane_dst = (nt*2 + (lk>>1))*16 + lm; elem off (lk&1)*4
    {
      const int ksg = w * 2 + half;
#pragma unroll
      for (int nt = 0; nt < 2; nt++) {
        int n0 = w * 64 + half * 32 + nt * 16 + lk * 4;
        f32x4 bv = *(const f32x4*)(bias + n0);
        int lane_dst = (nt * 2 + (lk >> 1)) * 16 + lm;
#pragma unroll
        for (int mf = 0; mf < 4; mf++) {
          f16x4 pv;
#pragma unroll
          for (int r = 0; r < 4; r++) pv[r] = (half_t)elu_f(acc[mf][nt][r] + bv[r]);
          *(f16x4*)(dst + ((size_t)(mf * 16 + ksg)) * 512 + lane_dst * 8 + (lk & 1) * 4) = pv;
        }
      }
    }
  }
}

// last GEMM: [64 x 512] (fragment-ordered A) @ [512 x 144] -> fp32 outb (row-major).
// 9 n-tiles over 8 waves: wave w -> tile w; wave 0 also tile 8.
__device__ __forceinline__ void gemm_out(
    const half_t* A,
    const half_t* __restrict__ Wf,        // [9*16 frags][512]
    const float* __restrict__ bias,       // [138]
    float* outb,
    int w, int lane, int lm, int lk) {
  f32x4 acc[4][2];
#pragma unroll
  for (int i = 0; i < 4; i++)
#pragma unroll
    for (int j = 0; j < 2; j++) acc[i][j] = (f32x4){0.f, 0.f, 0.f, 0.f};
  const bool has2 = (w == 0);

  f16x8 a[2][4], b[8][2];
#pragma unroll
  for (int s = 0; s < 8; s++) {
    b[s][0] = *(const f16x8*)(Wf + ((size_t)(w * 16 + s)) * 512 + lane * 8);
    if (has2) b[s][1] = *(const f16x8*)(Wf + ((size_t)(8 * 16 + s)) * 512 + lane * 8);
  }
#pragma unroll
  for (int s = 0; s < 2; s++) {
#pragma unroll
    for (int mf = 0; mf < 4; mf++)
      a[s][mf] = *(const f16x8*)(A + ((size_t)(mf * 16 + s)) * 512 + lane * 8);
  }
#pragma unroll
  for (int ks = 0; ks < 16; ks++) {
    const int sl = ks & 7, asx = ks & 1;
#pragma unroll
    for (int mf = 0; mf < 4; mf++)
      acc[mf][0] = __builtin_amdgcn_mfma_f32_16x16x32_f16(b[sl][0], a[asx][mf], acc[mf][0], 0, 0, 0);
    if (has2)
#pragma unroll
      for (int mf = 0; mf < 4; mf++)
        acc[mf][1] = __builtin_amdgcn_mfma_f32_16x16x32_f16(b[sl][1], a[asx][mf], acc[mf][1], 0, 0, 0);
    if (ks + 8 < 16) {
      b[sl][0] = *(const f16x8*)(Wf + ((size_t)(w * 16 + ks + 8)) * 512 + lane * 8);
      if (has2) b[sl][1] = *(const f16x8*)(Wf + ((size_t)(128 + ks + 8)) * 512 + lane * 8);
    }
    if (ks + 2 < 16) {
#pragma unroll
      for (int mf = 0; mf < 4; mf++)
        a[asx][mf] = *(const f16x8*)(A + ((size_t)(mf * 16 + ks + 2)) * 512 + lane * 8);
    }
  }
  // epilogue: aligned 16B stores; cols 138..143 get zeros (never read)
  {
    int n0 = w * 16 + lk * 4;
    f32x4 bv = *(const f32x4*)(bias + n0);
#pragma unroll
    for (int mf = 0; mf < 4; mf++) {
      f32x4 ov = acc[mf][0] + bv;
      *(f32x4*)(outb + (mf * 16 + lm) * OS + n0) = ov;
    }
  }
  if (has2) {
    int n0 = 128 + lk * 4;
    f32x4 bv;
#pragma unroll
    for (int r = 0; r < 4; r++) bv[r] = (n0 + r < 138) ? bias[n0 + r] : 0.f;
#pragma unroll
    for (int mf = 0; mf < 4; mf++) {
      f32x4 ov = acc[mf][1] + bv;
      *(f32x4*)(outb + (mf * 16 + lm) * OS + n0) = ov;
    }
  }
}

__global__ __launch_bounds__(NTH, 2) __attribute__((amdgpu_waves_per_eu(2, 2)))
void flow_kernel(const float* __restrict__ z, const float* __restrict__ c,
                 const float* __restrict__ b0, const float* __restrict__ b1,
                 const float* __restrict__ b2, const float* __restrict__ b3,
                 const int* __restrict__ perms,
                 const half_t* __restrict__ W0F, const half_t* __restrict__ W1F,
                 const half_t* __restrict__ W2F, const half_t* __restrict__ W3F,
                 float* __restrict__ out) {
  __shared__ half_t hbufA[4 * 16 * 512];                // 65,536 B (fragment-ordered)
  __shared__ __align__(16) char smemB[4 * 16 * 512 * 2];// 65,536 B: h frag-fp16 / out fp32 [MT][OS]
  __shared__ half_t inpb[4 * 512];                      // 4,096 B (fragment-ordered, KSA=1)
  __shared__ float xbuf[2][MT][12];                     // 6,144 B (ping-pong)
  __shared__ float ldtot[MT];
  __shared__ int   permbuf[7][12];
  __shared__ int   spldst[7][6];   // iperm[6+j]: dest col of spline output j
  __shared__ int   x1dst[7][6];    // j-th dest col k with perm[k] < 6

  half_t* hbufB  = (half_t*)smemB;
  float*  outbuf = (float*)smemB;

  int tid = threadIdx.x;
  int w = tid >> 6, lane = tid & 63;
  int lm = lane & 15, lk = lane >> 4;
  int row0 = blockIdx.x * MT;

  for (int it = tid; it < MT * 12; it += NTH) xbuf[0][it / 12][it % 12] = z[(size_t)row0 * 12 + it];
  for (int it = tid; it < 84; it += NTH) permbuf[it / 12][it % 12] = perms[it];
  // destination tables from global perms (no dependency on permbuf):
  if (tid < 42) {
    int l = tid / 6, j = tid % 6;
    int kx = 0, kj = 0, cnt = 0;
    for (int k = 0; k < 12; k++) {
      int p = perms[l * 12 + k];
      if (p == 6 + j) kx = k;
      if (p < 6) { if (cnt == j) kj = k; cnt++; }
    }
    spldst[l][j] = kx;
    x1dst[l][j]  = kj;
  }
  if (tid < MT) ldtot[tid] = 0.f;
  // build inpb ONCE: [x1(6) | c(16) | 0(10)] fp16, A-fragment order (KSA=1):
  // element (m,k) -> inpb[(m>>4)*512 + ((k>>3)*16 + (m&15))*8 + (k&7)]
  for (int it = tid; it < MT * 32; it += NTH) {
    int m = it >> 5, k = it & 31;
    half_t bv;
    if (k < 6)       bv = (half_t)z[(size_t)(row0 + m) * 12 + k];
    else if (k < 22) bv = (half_t)c[(size_t)(row0 + m) * 16 + (k - 6)];
    else             bv = (half_t)0.f;
    inpb[(m >> 4) * 512 + ((k >> 3) * 16 + (m & 15)) * 8 + (k & 7)] = bv;
  }
  __syncthreads();

  for (int l = 0; l < 8; l++) {
    const int cur = l & 1;
    gemm_elu(inpb, 1, 1,   W0F + (size_t)l * 32 * 512,     1,  b0 + l * 512, hbufA, w, lane, lm, lk);
    __syncthreads();
    gemm_elu(hbufA, 16, 16, W1F + (size_t)l * 512 * 512,  16,  b1 + l * 512, hbufB, w, lane, lm, lk);
    __syncthreads();
    gemm_elu(hbufB, 16, 16, W2F + (size_t)l * 512 * 512,  16,  b2 + l * 512, hbufA, w, lane, lm, lk);
    __syncthreads();
    gemm_out(hbufA, W3F + (size_t)l * 144 * 512, b3 + l * 138, outbuf, w, lane, lm, lk);
    __syncthreads();

    // ---- FUSED: spline + permute-scatter + logdet-atomic (one phase) ----
    if (tid < MT * 6) {
      int m = tid / 6, j = tid % 6;
      const float* pr = outbuf + m * OS + j * 23;
      float uw[8], uh[8], dd[9];
#pragma unroll
      for (int i = 0; i < 8; i++) uw[i] = pr[i];
#pragma unroll
      for (int i = 0; i < 8; i++) uh[i] = pr[8 + i];
      dd[0] = 1.f; dd[8] = 1.f;   // MIN_D + softplus(DERIV_CONST) == 1 exactly
#pragma unroll
      for (int i = 0; i < 7; i++) {
        float u = pr[16 + i];
        float sp = (u > 15.f) ? u : __logf(1.f + __expf(u));
        dd[i + 1] = 0.001f + sp;
      }
      float mw = uw[0];
#pragma unroll
      for (int i = 1; i < 8; i++) mw = fmaxf(mw, uw[i]);
      float ew[8], sw = 0.f;
#pragma unroll
      for (int i = 0; i < 8; i++) { ew[i] = __expf(uw[i] - mw); sw += ew[i]; }
      float invw = 1.f / sw;
      float cw[9]; cw[0] = -BND;
      float a = 0.f;
#pragma unroll
      for (int i = 0; i < 8; i++) { a += 0.001f + 0.992f * ew[i] * invw; cw[i + 1] = 2.f * BND * a - BND; }
      cw[8] = BND;
      float mh = uh[0];
#pragma unroll
      for (int i = 1; i < 8; i++) mh = fmaxf(mh, uh[i]);
      float eh[8], sh = 0.f;
#pragma unroll
      for (int i = 0; i < 8; i++) { eh[i] = __expf(uh[i] - mh); sh += eh[i]; }
      float invh = 1.f / sh;
      float ch[9]; ch[0] = -BND;
      float ah = 0.f;
#pragma unroll
      for (int i = 0; i < 8; i++) { ah += 0.001f + 0.992f * eh[i] * invh; ch[i + 1] = 2.f * BND * ah - BND; }
      ch[8] = BND;

      float x2 = xbuf[cur][m][6 + j];
      float xc = fminf(fmaxf(x2, -BND), BND);
      int cnt = 0;
#pragma unroll
      for (int i = 0; i < 9; i++) {
        float edge = (i == 8) ? (cw[8] + 1e-6f) : cw[i];
        cnt += (xc >= edge) ? 1 : 0;
      }
      int idx = cnt - 1; idx = idx < 0 ? 0 : (idx > 7 ? 7 : idx);
      float icw = cw[0], iw = cw[1] - cw[0], ich = ch[0], ih = ch[1] - ch[0], d0 = dd[0], d1 = dd[1];
#pragma unroll
      for (int i = 0; i < 8; i++) {
        if (idx == i) {
          icw = cw[i]; iw = cw[i + 1] - cw[i];
          ich = ch[i]; ih = ch[i + 1] - ch[i];
          d0 = dd[i]; d1 = dd[i + 1];
        }
      }
      float delta = ih / iw;
      float th  = (xc - icw) / iw;
      float t1m = th * (1.f - th);
      float num = ih * (delta * th * th + d0 * t1m);
      float den = delta + (d0 + d1 - 2.f * delta) * t1m;
      float outv = ich + num / den;
      float dnum = delta * delta * (d1 * th * th + 2.f * delta * t1m + d0 * (1.f - th) * (1.f - th));
      float lad = __logf(dnum) - 2.f * __logf(den);
      bool inside = (x2 >= -BND) && (x2 <= BND);
      float res  = inside ? outv : x2;
      float ladv = inside ? lad : 0.f;
      atomicAdd(&ldtot[m], ladv);
      if (l < 7) {
        // scatter spline output to its permuted destination
        int ko = spldst[l][j];
        xbuf[cur ^ 1][m][ko] = res;
        if (ko < 6) inpb[(m >> 4) * 512 + (m & 15) * 8 + ko] = (half_t)res;
        // copy the j-th x1-destination column (perm[kc] < 6: col unchanged this phase)
        int kc = x1dst[l][j];
        float xv = xbuf[cur][m][permbuf[l][kc]];
        xbuf[cur ^ 1][m][kc] = xv;
        if (kc < 6) inpb[(m >> 4) * 512 + (m & 15) * 8 + kc] = (half_t)xv;
      } else {
        xbuf[cur][m][6 + j] = res;   // last layer: in place, no permute
      }
    }
    __syncthreads();
  }

  for (int it = tid; it < MT * 12; it += NTH) out[(size_t)row0 * 12 + it] = xbuf[1][it / 12][it % 12];
  if (tid < MT) out[(size_t)NROWS * 12 + row0 + tid] = ldtot[tid];
}

extern "C" void kernel_launch(void* const* d_in, const int* in_sizes, int n_in,
                              void* d_out, int out_size, void* d_ws, size_t ws_size,
                              hipStream_t stream) {
  const float* z  = (const float*)d_in[0];
  const float* c  = (const float*)d_in[1];
  const float* W0 = (const float*)d_in[2];
  const float* b0 = (const float*)d_in[3];
  const float* W1 = (const float*)d_in[4];
  const float* b1 = (const float*)d_in[5];
  const float* W2 = (const float*)d_in[6];
  const float* b2 = (const float*)d_in[7];
  const float* W3 = (const float*)d_in[8];
  const float* b3 = (const float*)d_in[9];
  const int* perms = (const int*)d_in[10];

  unsigned short* wsu = (unsigned short*)d_ws;
  half_t* W0F = (half_t*)(wsu + 0);         // [8][32 frag][512]
  half_t* W1F = (half_t*)(wsu + 131072);    // [8][512 frag][512]
  half_t* W2F = (half_t*)(wsu + 2228224);   // [8][512 frag][512]
  half_t* W3F = (half_t*)(wsu + 4325376);   // [8][144 frag][512]

  // pack: 256 threads = 4 fragments per block
  pack_frag<<<dim3(8,   1, 8), dim3(256), 0, stream>>>(W0, W0F, 22,  512, 32, 1);
  pack_frag<<<dim3(128, 1, 8), dim3(256), 0, stream>>>(W1, W1F, 512, 512, 32, 16);
  pack_frag<<<dim3(128, 1, 8), dim3(256), 0, stream>>>(W2, W2F, 512, 512, 32, 16);
  pack_frag<<<dim3(36,  1, 8), dim3(256), 0, stream>>>(W3, W3F, 512, 138, 9,  16);

  flow_kernel<<<dim3(NROWS / MT), dim3(NTH), 0, stream>>>(
      z, c, b0, b1, b2, b3, perms, W0F, W1F, W2F, W3F, (float*)d_out);
}

// Round 18
// 465.437 us; speedup vs baseline: 1.0370x; 1.0370x over previous
//
#include <hip/hip_runtime.h>
#include <hip/hip_fp16.h>

// ---- problem constants ----
#define NROWS   32768
#define MT      64          // rows per block
#define NTH     512         // threads per block (8 waves; wave owns 64 cols, 2 passes of 32)
#define OS      148         // LDS out-params stride in float (138 + pad; 16B-aligned rows)
#define BND     3.0f

typedef _Float16 half_t;
typedef __attribute__((ext_vector_type(8))) _Float16 f16x8;
typedef __attribute__((ext_vector_type(4))) _Float16 f16x4;
typedef __attribute__((ext_vector_type(4))) float    f32x4;

// FINAL KERNEL (session best = R16): 409.7 us dispatch / 466.7 us bench,
// VGPR 112, no spill. vs session start 509.7 us: -8.4%.
// Structure: per layer {GEMM0 inpb->A, GEMM1 A->B, GEMM2 B->A, GEMM3
// A->outbuf, spline, permute} with 6 barriers; inpb built once in the
// prologue (c-cols layer-invariant), x1-col updates fused into the
// ping-pong permute.
// Session findings:
//  - __logf spline numerics (R5, +3.5%)
//  - W-ring depth 8 (R6)
//  - prologue inpb + ping-pong permute, 8->6 barriers (R16, +2.3%)
//  - ALLOCATOR LAW (R7-R12): regs/thread hard-capped at 2048/NTH;
//    launch_bounds arg2 / waves_per_eu / LDS do NOT steer it -> >128-reg
//    structures at NTH=512 spill (R9/R10/R12), NTH=1024 capped at 64 (R7/R8).
//  - 2-blocks/CU restructures fail deterministically, absmax=468 (R2-R4).
//  - 32x32x16 MFMA: equal pipe time, half the acc chains -> -20% (R14).
//  - fusing permute+logdet INTO the spline phase: +6us — work migrated
//    onto the 384-thread critical path (R17).

__global__ void pack_frag(const float* __restrict__ src, half_t* __restrict__ dst,
                          int K, int Nn, int NT, int KS) {
  int l = blockIdx.z;
  int frag = blockIdx.x * 4 + (threadIdx.x >> 6);
  int lane = threadIdx.x & 63;
  int NF = NT * KS;
  if (frag >= NF) return;
  int nt = frag / KS, ks = frag - nt * KS;
  int n = nt * 16 + (lane & 15);
  int kb = ks * 32 + (lane >> 4) * 8;
  f16x8 v;
#pragma unroll
  for (int e = 0; e < 8; e++) {
    int k = kb + e;
    v[e] = (k < K && n < Nn) ? (half_t)src[((size_t)l * K + k) * Nn + n] : (half_t)0.f;
  }
  *(f16x8*)(dst + ((size_t)l * NF + frag) * 512 + lane * 8) = v;
}

__device__ __forceinline__ float elu_f(float v) {
  return v > 0.f ? v : (__expf(v) - 1.f);
}

// GEMM: [64 x K] (LDS fp16, fragment-ordered, KSA ksteps) @ [K x 512] (global)
// -> elu(. + bias) -> dst LDS fp16 (fragment-ordered, 16 ksteps).
// Wave w covers cols [w*64, w*64+64) in TWO 32-col passes;
// pass 0's k-loop tail prefills pass 1's rings (all 8 lead steps).
// TRANSPOSED MFMA: mfma(W,A,acc) -> lane holds 4 consecutive n at row m.
__device__ __forceinline__ void gemm_elu(
    const half_t* A, int KSA, int ksteps,
    const half_t* __restrict__ Wf, int KSW,
    const float* __restrict__ bias,
    half_t* dst,
    int w, int lane, int lm, int lk) {
  f16x8 a[2][4], b[8][2];
#pragma unroll
  for (int half = 0; half < 2; half++) {
    const int ntb = w * 4 + half * 2;
    f32x4 acc[4][2];
#pragma unroll
    for (int i = 0; i < 4; i++)
#pragma unroll
      for (int j = 0; j < 2; j++) acc[i][j] = (f32x4){0.f, 0.f, 0.f, 0.f};

    const bool prefilled = (ksteps == 16) && (half == 1);
    if (!prefilled) {
#pragma unroll
      for (int s = 0; s < 8; s++)
        if (s < ksteps) {
#pragma unroll
          for (int nt = 0; nt < 2; nt++)
            b[s][nt] = *(const f16x8*)(Wf + ((size_t)((ntb + nt) * KSW + s)) * 512 + lane * 8);
        }
#pragma unroll
      for (int s = 0; s < 2; s++)
        if (s < ksteps) {
#pragma unroll
          for (int mf = 0; mf < 4; mf++)
            a[s][mf] = *(const f16x8*)(A + ((size_t)(mf * KSA + s)) * 512 + lane * 8);
        }
    }
#pragma unroll
    for (int ks = 0; ks < ksteps; ks++) {
      const int sl = ks & 7, asx = ks & 1;
#pragma unroll
      for (int nt = 0; nt < 2; nt++)
#pragma unroll
        for (int mf = 0; mf < 4; mf++)
          acc[mf][nt] = __builtin_amdgcn_mfma_f32_16x16x32_f16(b[sl][nt], a[asx][mf], acc[mf][nt], 0, 0, 0);
      // B refill: own steps (depth 8), then (pass 0 only) pass-1 steps 0..7
      if (ks + 8 < ksteps) {
#pragma unroll
        for (int nt = 0; nt < 2; nt++)
          b[sl][nt] = *(const f16x8*)(Wf + ((size_t)((ntb + nt) * KSW + ks + 8)) * 512 + lane * 8);
      } else if (ksteps == 16 && half == 0) {
#pragma unroll
        for (int nt = 0; nt < 2; nt++)
          b[sl][nt] = *(const f16x8*)(Wf + ((size_t)((ntb + 2 + nt) * KSW + (ks - 8))) * 512 + lane * 8);
      }
      // A refill: own chunks, then (pass 0 only) chunks 0..1 for pass 1
      if (ks + 2 < ksteps) {
#pragma unroll
        for (int mf = 0; mf < 4; mf++)
          a[asx][mf] = *(const f16x8*)(A + ((size_t)(mf * KSA + ks + 2)) * 512 + lane * 8);
      } else if (ksteps == 16 && half == 0) {
#pragma unroll
        for (int mf = 0; mf < 4; mf++)
          a[asx][mf] = *(const f16x8*)(A + ((size_t)(mf * KSA + (ks - 14))) * 512 + lane * 8);
      }
    }
    // epilogue -> dst in A-fragment order: element (m = mf*16+lm, k = n0+r)
    // frag = mf*16 + (w*2+half); lane_dst = (nt*2 + (lk>>1))*16 + lm; elem off (lk&1)*4
    {
      const int ksg = w * 2 + half;
#pragma unroll
      for (int nt = 0; nt < 2; nt++) {
        int n0 = w * 64 + half * 32 + nt * 16 + lk * 4;
        f32x4 bv = *(const f32x4*)(bias + n0);
        int lane_dst = (nt * 2 + (lk >> 1)) * 16 + lm;
#pragma unroll
        for (int mf = 0; mf < 4; mf++) {
          f16x4 pv;
#pragma unroll
          for (int r = 0; r < 4; r++) pv[r] = (half_t)elu_f(acc[mf][nt][r] + bv[r]);
          *(f16x4*)(dst + ((size_t)(mf * 16 + ksg)) * 512 + lane_dst * 8 + (lk & 1) * 4) = pv;
        }
      }
    }
  }
}

// last GEMM: [64 x 512] (fragment-ordered A) @ [512 x 144] -> fp32 outb (row-major).
// 9 n-tiles over 8 waves: wave w -> tile w; wave 0 also tile 8.
__device__ __forceinline__ void gemm_out(
    const half_t* A,
    const half_t* __restrict__ Wf,        // [9*16 frags][512]
    const float* __restrict__ bias,       // [138]
    float* outb,
    int w, int lane, int lm, int lk) {
  f32x4 acc[4][2];
#pragma unroll
  for (int i = 0; i < 4; i++)
#pragma unroll
    for (int j = 0; j < 2; j++) acc[i][j] = (f32x4){0.f, 0.f, 0.f, 0.f};
  const bool has2 = (w == 0);

  f16x8 a[2][4], b[8][2];
#pragma unroll
  for (int s = 0; s < 8; s++) {
    b[s][0] = *(const f16x8*)(Wf + ((size_t)(w * 16 + s)) * 512 + lane * 8);
    if (has2) b[s][1] = *(const f16x8*)(Wf + ((size_t)(8 * 16 + s)) * 512 + lane * 8);
  }
#pragma unroll
  for (int s = 0; s < 2; s++) {
#pragma unroll
    for (int mf = 0; mf < 4; mf++)
      a[s][mf] = *(const f16x8*)(A + ((size_t)(mf * 16 + s)) * 512 + lane * 8);
  }
#pragma unroll
  for (int ks = 0; ks < 16; ks++) {
    const int sl = ks & 7, asx = ks & 1;
#pragma unroll
    for (int mf = 0; mf < 4; mf++)
      acc[mf][0] = __builtin_amdgcn_mfma_f32_16x16x32_f16(b[sl][0], a[asx][mf], acc[mf][0], 0, 0, 0);
    if (has2)
#pragma unroll
      for (int mf = 0; mf < 4; mf++)
        acc[mf][1] = __builtin_amdgcn_mfma_f32_16x16x32_f16(b[sl][1], a[asx][mf], acc[mf][1], 0, 0, 0);
    if (ks + 8 < 16) {
      b[sl][0] = *(const f16x8*)(Wf + ((size_t)(w * 16 + ks + 8)) * 512 + lane * 8);
      if (has2) b[sl][1] = *(const f16x8*)(Wf + ((size_t)(128 + ks + 8)) * 512 + lane * 8);
    }
    if (ks + 2 < 16) {
#pragma unroll
      for (int mf = 0; mf < 4; mf++)
        a[asx][mf] = *(const f16x8*)(A + ((size_t)(mf * 16 + ks + 2)) * 512 + lane * 8);
    }
  }
  // epilogue: aligned 16B stores; cols 138..143 get zeros (never read)
  {
    int n0 = w * 16 + lk * 4;
    f32x4 bv = *(const f32x4*)(bias + n0);
#pragma unroll
    for (int mf = 0; mf < 4; mf++) {
      f32x4 ov = acc[mf][0] + bv;
      *(f32x4*)(outb + (mf * 16 + lm) * OS + n0) = ov;
    }
  }
  if (has2) {
    int n0 = 128 + lk * 4;
    f32x4 bv;
#pragma unroll
    for (int r = 0; r < 4; r++) bv[r] = (n0 + r < 138) ? bias[n0 + r] : 0.f;
#pragma unroll
    for (int mf = 0; mf < 4; mf++) {
      f32x4 ov = acc[mf][1] + bv;
      *(f32x4*)(outb + (mf * 16 + lm) * OS + n0) = ov;
    }
  }
}

__global__ __launch_bounds__(NTH, 2) __attribute__((amdgpu_waves_per_eu(2, 2)))
void flow_kernel(const float* __restrict__ z, const float* __restrict__ c,
                 const float* __restrict__ b0, const float* __restrict__ b1,
                 const float* __restrict__ b2, const float* __restrict__ b3,
                 const int* __restrict__ perms,
                 const half_t* __restrict__ W0F, const half_t* __restrict__ W1F,
                 const half_t* __restrict__ W2F, const half_t* __restrict__ W3F,
                 float* __restrict__ out) {
  __shared__ half_t hbufA[4 * 16 * 512];                // 65,536 B (fragment-ordered)
  __shared__ __align__(16) char smemB[4 * 16 * 512 * 2];// 65,536 B: h frag-fp16 / out fp32 [MT][OS]
  __shared__ half_t inpb[4 * 512];                      // 4,096 B (fragment-ordered, KSA=1)
  __shared__ float xbuf[2][MT][12];                     // 6,144 B (ping-pong)
  __shared__ float ldpart[MT][6];
  __shared__ float ldtot[MT];
  __shared__ int   permbuf[7][12];

  half_t* hbufB  = (half_t*)smemB;
  float*  outbuf = (float*)smemB;

  int tid = threadIdx.x;
  int w = tid >> 6, lane = tid & 63;
  int lm = lane & 15, lk = lane >> 4;
  int row0 = blockIdx.x * MT;

  for (int it = tid; it < MT * 12; it += NTH) xbuf[0][it / 12][it % 12] = z[(size_t)row0 * 12 + it];
  for (int it = tid; it < 84; it += NTH) permbuf[it / 12][it % 12] = perms[it];
  if (tid < MT) ldtot[tid] = 0.f;
  // build inpb ONCE: [x1(6) | c(16) | 0(10)] fp16, A-fragment order (KSA=1):
  // element (m,k) -> inpb[(m>>4)*512 + ((k>>3)*16 + (m&15))*8 + (k&7)]
  // (x1/c read straight from global; cols >=6 never rewritten again)
  for (int it = tid; it < MT * 32; it += NTH) {
    int m = it >> 5, k = it & 31;
    half_t bv;
    if (k < 6)       bv = (half_t)z[(size_t)(row0 + m) * 12 + k];
    else if (k < 22) bv = (half_t)c[(size_t)(row0 + m) * 16 + (k - 6)];
    else             bv = (half_t)0.f;
    inpb[(m >> 4) * 512 + ((k >> 3) * 16 + (m & 15)) * 8 + (k & 7)] = bv;
  }
  __syncthreads();

  for (int l = 0; l < 8; l++) {
    const int cur = l & 1;
    gemm_elu(inpb, 1, 1,   W0F + (size_t)l * 32 * 512,     1,  b0 + l * 512, hbufA, w, lane, lm, lk);
    __syncthreads();
    gemm_elu(hbufA, 16, 16, W1F + (size_t)l * 512 * 512,  16,  b1 + l * 512, hbufB, w, lane, lm, lk);
    __syncthreads();
    gemm_elu(hbufB, 16, 16, W2F + (size_t)l * 512 * 512,  16,  b2 + l * 512, hbufA, w, lane, lm, lk);
    __syncthreads();
    gemm_out(hbufA, W3F + (size_t)l * 144 * 512, b3 + l * 138, outbuf, w, lane, lm, lk);
    __syncthreads();

    // ---- rational-quadratic spline, one thread per (row, dim) ----
    if (tid < MT * 6) {
      int m = tid / 6, j = tid % 6;
      const float* pr = outbuf + m * OS + j * 23;
      float uw[8], uh[8], dd[9];
#pragma unroll
      for (int i = 0; i < 8; i++) uw[i] = pr[i];
#pragma unroll
      for (int i = 0; i < 8; i++) uh[i] = pr[8 + i];
      dd[0] = 1.f; dd[8] = 1.f;   // MIN_D + softplus(DERIV_CONST) == 1 exactly
#pragma unroll
      for (int i = 0; i < 7; i++) {
        float u = pr[16 + i];
        float sp = (u > 15.f) ? u : __logf(1.f + __expf(u));
        dd[i + 1] = 0.001f + sp;
      }
      float mw = uw[0];
#pragma unroll
      for (int i = 1; i < 8; i++) mw = fmaxf(mw, uw[i]);
      float ew[8], sw = 0.f;
#pragma unroll
      for (int i = 0; i < 8; i++) { ew[i] = __expf(uw[i] - mw); sw += ew[i]; }
      float invw = 1.f / sw;
      float cw[9]; cw[0] = -BND;
      float a = 0.f;
#pragma unroll
      for (int i = 0; i < 8; i++) { a += 0.001f + 0.992f * ew[i] * invw; cw[i + 1] = 2.f * BND * a - BND; }
      cw[8] = BND;
      float mh = uh[0];
#pragma unroll
      for (int i = 1; i < 8; i++) mh = fmaxf(mh, uh[i]);
      float eh[8], sh = 0.f;
#pragma unroll
      for (int i = 0; i < 8; i++) { eh[i] = __expf(uh[i] - mh); sh += eh[i]; }
      float invh = 1.f / sh;
      float ch[9]; ch[0] = -BND;
      float ah = 0.f;
#pragma unroll
      for (int i = 0; i < 8; i++) { ah += 0.001f + 0.992f * eh[i] * invh; ch[i + 1] = 2.f * BND * ah - BND; }
      ch[8] = BND;

      float x2 = xbuf[cur][m][6 + j];
      float xc = fminf(fmaxf(x2, -BND), BND);
      int cnt = 0;
#pragma unroll
      for (int i = 0; i < 9; i++) {
        float edge = (i == 8) ? (cw[8] + 1e-6f) : cw[i];
        cnt += (xc >= edge) ? 1 : 0;
      }
      int idx = cnt - 1; idx = idx < 0 ? 0 : (idx > 7 ? 7 : idx);
      float icw = cw[0], iw = cw[1] - cw[0], ich = ch[0], ih = ch[1] - ch[0], d0 = dd[0], d1 = dd[1];
#pragma unroll
      for (int i = 0; i < 8; i++) {
        if (idx == i) {
          icw = cw[i]; iw = cw[i + 1] - cw[i];
          ich = ch[i]; ih = ch[i + 1] - ch[i];
          d0 = dd[i]; d1 = dd[i + 1];
        }
      }
      float delta = ih / iw;
      float th  = (xc - icw) / iw;
      float t1m = th * (1.f - th);
      float num = ih * (delta * th * th + d0 * t1m);
      float den = delta + (d0 + d1 - 2.f * delta) * t1m;
      float outv = ich + num / den;
      float dnum = delta * delta * (d1 * th * th + 2.f * delta * t1m + d0 * (1.f - th) * (1.f - th));
      float lad = __logf(dnum) - 2.f * __logf(den);
      bool inside = (x2 >= -BND) && (x2 <= BND);
      xbuf[cur][m][6 + j] = inside ? outv : x2;
      ldpart[m][j]   = inside ? lad : 0.f;
    }
    __syncthreads();
    if (tid < MT) {
      float s = ldtot[tid];
#pragma unroll
      for (int j = 0; j < 6; j++) s += ldpart[tid][j];
      ldtot[tid] = s;
    }
    if (l < 7) {
      // permute xbuf[cur] -> xbuf[cur^1] (no internal barrier: ping-pong),
      // fusing the 6 x1-col updates of inpb for the next layer's GEMM0.
      int m0 = tid / 12, k0 = tid % 12;
      float v0 = xbuf[cur][m0][permbuf[l][k0]];
      int it1 = tid + NTH;
      int m1 = it1 / 12, k1 = it1 % 12;
      float v1 = (it1 < MT * 12) ? xbuf[cur][m1][permbuf[l][k1]] : 0.f;
      xbuf[cur ^ 1][m0][k0] = v0;
      if (k0 < 6) inpb[(m0 >> 4) * 512 + (m0 & 15) * 8 + k0] = (half_t)v0;
      if (it1 < MT * 12) {
        xbuf[cur ^ 1][m1][k1] = v1;
        if (k1 < 6) inpb[(m1 >> 4) * 512 + (m1 & 15) * 8 + k1] = (half_t)v1;
      }
    }
    __syncthreads();
  }

  for (int it = tid; it < MT * 12; it += NTH) out[(size_t)row0 * 12 + it] = xbuf[1][it / 12][it % 12];
  if (tid < MT) out[(size_t)NROWS * 12 + row0 + tid] = ldtot[tid];
}

extern "C" void kernel_launch(void* const* d_in, const int* in_sizes, int n_in,
                              void* d_out, int out_size, void* d_ws, size_t ws_size,
                              hipStream_t stream) {
  const float* z  = (const float*)d_in[0];
  const float* c  = (const float*)d_in[1];
  const float* W0 = (const float*)d_in[2];
  const float* b0 = (const float*)d_in[3];
  const float* W1 = (const float*)d_in[4];
  const float* b1 = (const float*)d_in[5];
  const float* W2 = (const float*)d_in[6];
  const float* b2 = (const float*)d_in[7];
  const float* W3 = (const float*)d_in[8];
  const float* b3 = (const float*)d_in[9];
  const int* perms = (const int*)d_in[10];

  unsigned short* wsu = (unsigned short*)d_ws;
  half_t* W0F = (half_t*)(wsu + 0);         // [8][32 frag][512]
  half_t* W1F = (half_t*)(wsu + 131072);    // [8][512 frag][512]
  half_t* W2F = (half_t*)(wsu + 2228224);   // [8][512 frag][512]
  half_t* W3F = (half_t*)(wsu + 4325376);   // [8][144 frag][512]

  // pack: 256 threads = 4 fragments per block
  pack_frag<<<dim3(8,   1, 8), dim3(256), 0, stream>>>(W0, W0F, 22,  512, 32, 1);
  pack_frag<<<dim3(128, 1, 8), dim3(256), 0, stream>>>(W1, W1F, 512, 512, 32, 16);
  pack_frag<<<dim3(128, 1, 8), dim3(256), 0, stream>>>(W2, W2F, 512, 512, 32, 16);
  pack_frag<<<dim3(36,  1, 8), dim3(256), 0, stream>>>(W3, W3F, 512, 138, 9,  16);

  flow_kernel<<<dim3(NROWS / MT), dim3(NTH), 0, stream>>>(
      z, c, b0, b1, b2, b3, perms, W0F, W1F, W2F, W3F, (float*)d_out);
}

// Round 19
// 463.739 us; speedup vs baseline: 1.0408x; 1.0037x over previous
//
#include <hip/hip_runtime.h>
#include <hip/hip_fp16.h>

// ---- problem constants ----
#define NROWS   32768
#define MT      64          // rows per block
#define NTH     512         // threads per block (8 waves; wave owns 64 cols, 2 passes of 32)
#define OS      148         // LDS out-params stride in float (138 + pad; 16B-aligned rows)
#define BND     3.0f

typedef _Float16 half_t;
typedef __attribute__((ext_vector_type(8))) _Float16 f16x8;
typedef __attribute__((ext_vector_type(4))) _Float16 f16x4;
typedef __attribute__((ext_vector_type(4))) float    f32x4;

// R19 = R16 flow kernel (verified best: 407-410 us dispatch) + MERGED pack
// stage: the four pack_frag launches (serialized, ~57 us of bench-vs-
// dispatch gap) become ONE pack_all kernel with partitioned blockIdx.x
// (8+128+128+36 = 300 x-blocks x 8 layers) so all four weight repacks run
// concurrently and 3 launch/graph-node overheads disappear. Inner pack
// logic byte-identical; flow kernel untouched.
// Session findings carried:
//  - __logf spline numerics (R5), W-ring depth 8 (R6)
//  - prologue inpb + ping-pong permute, 8->6 barriers (R16)
//  - ALLOCATOR LAW (R7-R12): regs/thread = 2048/NTH hard cap
//  - 2-blk/CU restructures fail w/ absmax=468 (R2-R4); 32x32 MFMA -20%
//    (R14); spline-phase fusion +6us critical-path migration (R17).

__device__ __forceinline__ void pack_one(
    const float* __restrict__ src, half_t* __restrict__ dst,
    int K, int Nn, int NT, int KS, int bx, int l, int tid) {
  int frag = bx * 4 + (tid >> 6);
  int lane = tid & 63;
  int NF = NT * KS;
  if (frag >= NF) return;
  int nt = frag / KS, ks = frag - nt * KS;
  int n = nt * 16 + (lane & 15);
  int kb = ks * 32 + (lane >> 4) * 8;
  f16x8 v;
#pragma unroll
  for (int e = 0; e < 8; e++) {
    int k = kb + e;
    v[e] = (k < K && n < Nn) ? (half_t)src[((size_t)l * K + k) * Nn + n] : (half_t)0.f;
  }
  *(f16x8*)(dst + ((size_t)l * NF + frag) * 512 + lane * 8) = v;
}

__global__ void pack_all(const float* __restrict__ W0, const float* __restrict__ W1,
                         const float* __restrict__ W2, const float* __restrict__ W3,
                         half_t* __restrict__ W0F, half_t* __restrict__ W1F,
                         half_t* __restrict__ W2F, half_t* __restrict__ W3F) {
  int bx = blockIdx.x, l = blockIdx.z, tid = threadIdx.x;
  if (bx < 8)        pack_one(W0, W0F, 22,  512, 32, 1,  bx,       l, tid);
  else if (bx < 136) pack_one(W1, W1F, 512, 512, 32, 16, bx - 8,   l, tid);
  else if (bx < 264) pack_one(W2, W2F, 512, 512, 32, 16, bx - 136, l, tid);
  else               pack_one(W3, W3F, 512, 138, 9,  16, bx - 264, l, tid);
}

__device__ __forceinline__ float elu_f(float v) {
  return v > 0.f ? v : (__expf(v) - 1.f);
}

// GEMM: [64 x K] (LDS fp16, fragment-ordered, KSA ksteps) @ [K x 512] (global)
// -> elu(. + bias) -> dst LDS fp16 (fragment-ordered, 16 ksteps).
// Wave w covers cols [w*64, w*64+64) in TWO 32-col passes;
// pass 0's k-loop tail prefills pass 1's rings (all 8 lead steps).
// TRANSPOSED MFMA: mfma(W,A,acc) -> lane holds 4 consecutive n at row m.
__device__ __forceinline__ void gemm_elu(
    const half_t* A, int KSA, int ksteps,
    const half_t* __restrict__ Wf, int KSW,
    const float* __restrict__ bias,
    half_t* dst,
    int w, int lane, int lm, int lk) {
  f16x8 a[2][4], b[8][2];
#pragma unroll
  for (int half = 0; half < 2; half++) {
    const int ntb = w * 4 + half * 2;
    f32x4 acc[4][2];
#pragma unroll
    for (int i = 0; i < 4; i++)
#pragma unroll
      for (int j = 0; j < 2; j++) acc[i][j] = (f32x4){0.f, 0.f, 0.f, 0.f};

    const bool prefilled = (ksteps == 16) && (half == 1);
    if (!prefilled) {
#pragma unroll
      for (int s = 0; s < 8; s++)
        if (s < ksteps) {
#pragma unroll
          for (int nt = 0; nt < 2; nt++)
            b[s][nt] = *(const f16x8*)(Wf + ((size_t)((ntb + nt) * KSW + s)) * 512 + lane * 8);
        }
#pragma unroll
      for (int s = 0; s < 2; s++)
        if (s < ksteps) {
#pragma unroll
          for (int mf = 0; mf < 4; mf++)
            a[s][mf] = *(const f16x8*)(A + ((size_t)(mf * KSA + s)) * 512 + lane * 8);
        }
    }
#pragma unroll
    for (int ks = 0; ks < ksteps; ks++) {
      const int sl = ks & 7, asx = ks & 1;
#pragma unroll
      for (int nt = 0; nt < 2; nt++)
#pragma unroll
        for (int mf = 0; mf < 4; mf++)
          acc[mf][nt] = __builtin_amdgcn_mfma_f32_16x16x32_f16(b[sl][nt], a[asx][mf], acc[mf][nt], 0, 0, 0);
      // B refill: own steps (depth 8), then (pass 0 only) pass-1 steps 0..7
      if (ks + 8 < ksteps) {
#pragma unroll
        for (int nt = 0; nt < 2; nt++)
          b[sl][nt] = *(const f16x8*)(Wf + ((size_t)((ntb + nt) * KSW + ks + 8)) * 512 + lane * 8);
      } else if (ksteps == 16 && half == 0) {
#pragma unroll
        for (int nt = 0; nt < 2; nt++)
          b[sl][nt] = *(const f16x8*)(Wf + ((size_t)((ntb + 2 + nt) * KSW + (ks - 8))) * 512 + lane * 8);
      }
      // A refill: own chunks, then (pass 0 only) chunks 0..1 for pass 1
      if (ks + 2 < ksteps) {
#pragma unroll
        for (int mf = 0; mf < 4; mf++)
          a[asx][mf] = *(const f16x8*)(A + ((size_t)(mf * KSA + ks + 2)) * 512 + lane * 8);
      } else if (ksteps == 16 && half == 0) {
#pragma unroll
        for (int mf = 0; mf < 4; mf++)
          a[asx][mf] = *(const f16x8*)(A + ((size_t)(mf * KSA + (ks - 14))) * 512 + lane * 8);
      }
    }
    // epilogue -> dst in A-fragment order: element (m = mf*16+lm, k = n0+r)
    // frag = mf*16 + (w*2+half); lane_dst = (nt*2 + (lk>>1))*16 + lm; elem off (lk&1)*4
    {
      const int ksg = w * 2 + half;
#pragma unroll
      for (int nt = 0; nt < 2; nt++) {
        int n0 = w * 64 + half * 32 + nt * 16 + lk * 4;
        f32x4 bv = *(const f32x4*)(bias + n0);
        int lane_dst = (nt * 2 + (lk >> 1)) * 16 + lm;
#pragma unroll
        for (int mf = 0; mf < 4; mf++) {
          f16x4 pv;
#pragma unroll
          for (int r = 0; r < 4; r++) pv[r] = (half_t)elu_f(acc[mf][nt][r] + bv[r]);
          *(f16x4*)(dst + ((size_t)(mf * 16 + ksg)) * 512 + lane_dst * 8 + (lk & 1) * 4) = pv;
        }
      }
    }
  }
}

// last GEMM: [64 x 512] (fragment-ordered A) @ [512 x 144] -> fp32 outb (row-major).
// 9 n-tiles over 8 waves: wave w -> tile w; wave 0 also tile 8.
__device__ __forceinline__ void gemm_out(
    const half_t* A,
    const half_t* __restrict__ Wf,        // [9*16 frags][512]
    const float* __restrict__ bias,       // [138]
    float* outb,
    int w, int lane, int lm, int lk) {
  f32x4 acc[4][2];
#pragma unroll
  for (int i = 0; i < 4; i++)
#pragma unroll
    for (int j = 0; j < 2; j++) acc[i][j] = (f32x4){0.f, 0.f, 0.f, 0.f};
  const bool has2 = (w == 0);

  f16x8 a[2][4], b[8][2];
#pragma unroll
  for (int s = 0; s < 8; s++) {
    b[s][0] = *(const f16x8*)(Wf + ((size_t)(w * 16 + s)) * 512 + lane * 8);
    if (has2) b[s][1] = *(const f16x8*)(Wf + ((size_t)(8 * 16 + s)) * 512 + lane * 8);
  }
#pragma unroll
  for (int s = 0; s < 2; s++) {
#pragma unroll
    for (int mf = 0; mf < 4; mf++)
      a[s][mf] = *(const f16x8*)(A + ((size_t)(mf * 16 + s)) * 512 + lane * 8);
  }
#pragma unroll
  for (int ks = 0; ks < 16; ks++) {
    const int sl = ks & 7, asx = ks & 1;
#pragma unroll
    for (int mf = 0; mf < 4; mf++)
      acc[mf][0] = __builtin_amdgcn_mfma_f32_16x16x32_f16(b[sl][0], a[asx][mf], acc[mf][0], 0, 0, 0);
    if (has2)
#pragma unroll
      for (int mf = 0; mf < 4; mf++)
        acc[mf][1] = __builtin_amdgcn_mfma_f32_16x16x32_f16(b[sl][1], a[asx][mf], acc[mf][1], 0, 0, 0);
    if (ks + 8 < 16) {
      b[sl][0] = *(const f16x8*)(Wf + ((size_t)(w * 16 + ks + 8)) * 512 + lane * 8);
      if (has2) b[sl][1] = *(const f16x8*)(Wf + ((size_t)(128 + ks + 8)) * 512 + lane * 8);
    }
    if (ks + 2 < 16) {
#pragma unroll
      for (int mf = 0; mf < 4; mf++)
        a[asx][mf] = *(const f16x8*)(A + ((size_t)(mf * 16 + ks + 2)) * 512 + lane * 8);
    }
  }
  // epilogue: aligned 16B stores; cols 138..143 get zeros (never read)
  {
    int n0 = w * 16 + lk * 4;
    f32x4 bv = *(const f32x4*)(bias + n0);
#pragma unroll
    for (int mf = 0; mf < 4; mf++) {
      f32x4 ov = acc[mf][0] + bv;
      *(f32x4*)(outb + (mf * 16 + lm) * OS + n0) = ov;
    }
  }
  if (has2) {
    int n0 = 128 + lk * 4;
    f32x4 bv;
#pragma unroll
    for (int r = 0; r < 4; r++) bv[r] = (n0 + r < 138) ? bias[n0 + r] : 0.f;
#pragma unroll
    for (int mf = 0; mf < 4; mf++) {
      f32x4 ov = acc[mf][1] + bv;
      *(f32x4*)(outb + (mf * 16 + lm) * OS + n0) = ov;
    }
  }
}

__global__ __launch_bounds__(NTH, 2) __attribute__((amdgpu_waves_per_eu(2, 2)))
void flow_kernel(const float* __restrict__ z, const float* __restrict__ c,
                 const float* __restrict__ b0, const float* __restrict__ b1,
                 const float* __restrict__ b2, const float* __restrict__ b3,
                 const int* __restrict__ perms,
                 const half_t* __restrict__ W0F, const half_t* __restrict__ W1F,
                 const half_t* __restrict__ W2F, const half_t* __restrict__ W3F,
                 float* __restrict__ out) {
  __shared__ half_t hbufA[4 * 16 * 512];                // 65,536 B (fragment-ordered)
  __shared__ __align__(16) char smemB[4 * 16 * 512 * 2];// 65,536 B: h frag-fp16 / out fp32 [MT][OS]
  __shared__ half_t inpb[4 * 512];                      // 4,096 B (fragment-ordered, KSA=1)
  __shared__ float xbuf[2][MT][12];                     // 6,144 B (ping-pong)
  __shared__ float ldpart[MT][6];
  __shared__ float ldtot[MT];
  __shared__ int   permbuf[7][12];

  half_t* hbufB  = (half_t*)smemB;
  float*  outbuf = (float*)smemB;

  int tid = threadIdx.x;
  int w = tid >> 6, lane = tid & 63;
  int lm = lane & 15, lk = lane >> 4;
  int row0 = blockIdx.x * MT;

  for (int it = tid; it < MT * 12; it += NTH) xbuf[0][it / 12][it % 12] = z[(size_t)row0 * 12 + it];
  for (int it = tid; it < 84; it += NTH) permbuf[it / 12][it % 12] = perms[it];
  if (tid < MT) ldtot[tid] = 0.f;
  // build inpb ONCE: [x1(6) | c(16) | 0(10)] fp16, A-fragment order (KSA=1):
  // element (m,k) -> inpb[(m>>4)*512 + ((k>>3)*16 + (m&15))*8 + (k&7)]
  // (x1/c read straight from global; cols >=6 never rewritten again)
  for (int it = tid; it < MT * 32; it += NTH) {
    int m = it >> 5, k = it & 31;
    half_t bv;
    if (k < 6)       bv = (half_t)z[(size_t)(row0 + m) * 12 + k];
    else if (k < 22) bv = (half_t)c[(size_t)(row0 + m) * 16 + (k - 6)];
    else             bv = (half_t)0.f;
    inpb[(m >> 4) * 512 + ((k >> 3) * 16 + (m & 15)) * 8 + (k & 7)] = bv;
  }
  __syncthreads();

  for (int l = 0; l < 8; l++) {
    const int cur = l & 1;
    gemm_elu(inpb, 1, 1,   W0F + (size_t)l * 32 * 512,     1,  b0 + l * 512, hbufA, w, lane, lm, lk);
    __syncthreads();
    gemm_elu(hbufA, 16, 16, W1F + (size_t)l * 512 * 512,  16,  b1 + l * 512, hbufB, w, lane, lm, lk);
    __syncthreads();
    gemm_elu(hbufB, 16, 16, W2F + (size_t)l * 512 * 512,  16,  b2 + l * 512, hbufA, w, lane, lm, lk);
    __syncthreads();
    gemm_out(hbufA, W3F + (size_t)l * 144 * 512, b3 + l * 138, outbuf, w, lane, lm, lk);
    __syncthreads();

    // ---- rational-quadratic spline, one thread per (row, dim) ----
    if (tid < MT * 6) {
      int m = tid / 6, j = tid % 6;
      const float* pr = outbuf + m * OS + j * 23;
      float uw[8], uh[8], dd[9];
#pragma unroll
      for (int i = 0; i < 8; i++) uw[i] = pr[i];
#pragma unroll
      for (int i = 0; i < 8; i++) uh[i] = pr[8 + i];
      dd[0] = 1.f; dd[8] = 1.f;   // MIN_D + softplus(DERIV_CONST) == 1 exactly
#pragma unroll
      for (int i = 0; i < 7; i++) {
        float u = pr[16 + i];
        float sp = (u > 15.f) ? u : __logf(1.f + __expf(u));
        dd[i + 1] = 0.001f + sp;
      }
      float mw = uw[0];
#pragma unroll
      for (int i = 1; i < 8; i++) mw = fmaxf(mw, uw[i]);
      float ew[8], sw = 0.f;
#pragma unroll
      for (int i = 0; i < 8; i++) { ew[i] = __expf(uw[i] - mw); sw += ew[i]; }
      float invw = 1.f / sw;
      float cw[9]; cw[0] = -BND;
      float a = 0.f;
#pragma unroll
      for (int i = 0; i < 8; i++) { a += 0.001f + 0.992f * ew[i] * invw; cw[i + 1] = 2.f * BND * a - BND; }
      cw[8] = BND;
      float mh = uh[0];
#pragma unroll
      for (int i = 1; i < 8; i++) mh = fmaxf(mh, uh[i]);
      float eh[8], sh = 0.f;
#pragma unroll
      for (int i = 0; i < 8; i++) { eh[i] = __expf(uh[i] - mh); sh += eh[i]; }
      float invh = 1.f / sh;
      float ch[9]; ch[0] = -BND;
      float ah = 0.f;
#pragma unroll
      for (int i = 0; i < 8; i++) { ah += 0.001f + 0.992f * eh[i] * invh; ch[i + 1] = 2.f * BND * ah - BND; }
      ch[8] = BND;

      float x2 = xbuf[cur][m][6 + j];
      float xc = fminf(fmaxf(x2, -BND), BND);
      int cnt = 0;
#pragma unroll
      for (int i = 0; i < 9; i++) {
        float edge = (i == 8) ? (cw[8] + 1e-6f) : cw[i];
        cnt += (xc >= edge) ? 1 : 0;
      }
      int idx = cnt - 1; idx = idx < 0 ? 0 : (idx > 7 ? 7 : idx);
      float icw = cw[0], iw = cw[1] - cw[0], ich = ch[0], ih = ch[1] - ch[0], d0 = dd[0], d1 = dd[1];
#pragma unroll
      for (int i = 0; i < 8; i++) {
        if (idx == i) {
          icw = cw[i]; iw = cw[i + 1] - cw[i];
          ich = ch[i]; ih = ch[i + 1] - ch[i];
          d0 = dd[i]; d1 = dd[i + 1];
        }
      }
      float delta = ih / iw;
      float th  = (xc - icw) / iw;
      float t1m = th * (1.f - th);
      float num = ih * (delta * th * th + d0 * t1m);
      float den = delta + (d0 + d1 - 2.f * delta) * t1m;
      float outv = ich + num / den;
      float dnum = delta * delta * (d1 * th * th + 2.f * delta * t1m + d0 * (1.f - th) * (1.f - th));
      float lad = __logf(dnum) - 2.f * __logf(den);
      bool inside = (x2 >= -BND) && (x2 <= BND);
      xbuf[cur][m][6 + j] = inside ? outv : x2;
      ldpart[m][j]   = inside ? lad : 0.f;
    }
    __syncthreads();
    if (tid < MT) {
      float s = ldtot[tid];
#pragma unroll
      for (int j = 0; j < 6; j++) s += ldpart[tid][j];
      ldtot[tid] = s;
    }
    if (l < 7) {
      // permute xbuf[cur] -> xbuf[cur^1] (no internal barrier: ping-pong),
      // fusing the 6 x1-col updates of inpb for the next layer's GEMM0.
      int m0 = tid / 12, k0 = tid % 12;
      float v0 = xbuf[cur][m0][permbuf[l][k0]];
      int it1 = tid + NTH;
      int m1 = it1 / 12, k1 = it1 % 12;
      float v1 = (it1 < MT * 12) ? xbuf[cur][m1][permbuf[l][k1]] : 0.f;
      xbuf[cur ^ 1][m0][k0] = v0;
      if (k0 < 6) inpb[(m0 >> 4) * 512 + (m0 & 15) * 8 + k0] = (half_t)v0;
      if (it1 < MT * 12) {
        xbuf[cur ^ 1][m1][k1] = v1;
        if (k1 < 6) inpb[(m1 >> 4) * 512 + (m1 & 15) * 8 + k1] = (half_t)v1;
      }
    }
    __syncthreads();
  }

  for (int it = tid; it < MT * 12; it += NTH) out[(size_t)row0 * 12 + it] = xbuf[1][it / 12][it % 12];
  if (tid < MT) out[(size_t)NROWS * 12 + row0 + tid] = ldtot[tid];
}

extern "C" void kernel_launch(void* const* d_in, const int* in_sizes, int n_in,
                              void* d_out, int out_size, void* d_ws, size_t ws_size,
                              hipStream_t stream) {
  const float* z  = (const float*)d_in[0];
  const float* c  = (const float*)d_in[1];
  const float* W0 = (const float*)d_in[2];
  const float* b0 = (const float*)d_in[3];
  const float* W1 = (const float*)d_in[4];
  const float* b1 = (const float*)d_in[5];
  const float* W2 = (const float*)d_in[6];
  const float* b2 = (const float*)d_in[7];
  const float* W3 = (const float*)d_in[8];
  const float* b3 = (const float*)d_in[9];
  const int* perms = (const int*)d_in[10];

  unsigned short* wsu = (unsigned short*)d_ws;
  half_t* W0F = (half_t*)(wsu + 0);         // [8][32 frag][512]
  half_t* W1F = (half_t*)(wsu + 131072);    // [8][512 frag][512]
  half_t* W2F = (half_t*)(wsu + 2228224);   // [8][512 frag][512]
  half_t* W3F = (half_t*)(wsu + 4325376);   // [8][144 frag][512]

  // single merged pack launch: x-blocks 0..7 -> W0, 8..135 -> W1,
  // 136..263 -> W2, 264..299 -> W3; z = layer. 256 thr = 4 frags/block.
  pack_all<<<dim3(300, 1, 8), dim3(256), 0, stream>>>(
      W0, W1, W2, W3, W0F, W1F, W2F, W3F);

  flow_kernel<<<dim3(NROWS / MT), dim3(NTH), 0, stream>>>(
      z, c, b0, b1, b2, b3, perms, W0F, W1F, W2F, W3F, (float*)d_out);
}